// Round 12
// baseline (614.932 us; speedup 1.0000x reference)
//
#include <hip/hip_runtime.h>

#define B_     4
#define T_     4096
#define C_     1024
#define H_     4096
#define BT_    (B_ * T_)
#define NCH_   64
#define CHLEN_ 64
#define MCHUNK 8192   // rows per h-chunk for GEMM2a/2b (2 chunks)

typedef __bf16 bf16_t;
typedef __bf16 bf16x8 __attribute__((ext_vector_type(8)));
typedef float  f32x4  __attribute__((ext_vector_type(4)));

__device__ __forceinline__ float hs_f(float v) {
    return fminf(fmaxf((v + 3.0f) * (1.0f / 6.0f), 0.0f), 1.0f) - 0.5f;
}

__device__ __forceinline__ void gld_lds16(const bf16_t* g, bf16_t* l) {
    __builtin_amdgcn_global_load_lds((const __attribute__((address_space(1))) void*)g,
                                     (__attribute__((address_space(3))) void*)l,
                                     16, 0, 0);
}

// ---------------------------------------------------------------------------
__global__ __launch_bounds__(256) void rms_rows_f32(const float* __restrict__ X,
                                                    float* __restrict__ inv) {
    const int wave = threadIdx.x >> 6, lane = threadIdx.x & 63;
    const int row = blockIdx.x * 4 + wave;
    const float* xr = X + (size_t)row * C_;
    float s = 0.0f;
    #pragma unroll
    for (int p = 0; p < 4; p++) {
        float4 v = *(const float4*)(xr + p * 256 + lane * 4);
        s += v.x * v.x + v.y * v.y + v.z * v.z + v.w * v.w;
    }
    #pragma unroll
    for (int o = 32; o > 0; o >>= 1) s += __shfl_down(s, o, 64);
    if (lane == 0) inv[row] = rsqrtf(s * (1.0f / C_) + 1e-6f);
}

// ---------------------------------------------------------------------------
__global__ __launch_bounds__(256) void scan_emit_local(const float* __restrict__ X,
                                                       const float* __restrict__ inv1,
                                                       const float* __restrict__ nw,
                                                       bf16_t* __restrict__ state,
                                                       float* __restrict__ csum) {
    const int bch = blockIdx.x;
    const int b = bch >> 6, ch = bch & 63;
    const int c = blockIdx.y * 256 + threadIdx.x;
    const float wgt = nw[c];
    const int rbase = b * T_ + ch * CHLEN_;
    const size_t xbase = (size_t)rbase * C_ + c;
    float acc = 0.0f;
    for (int i = 0; i < CHLEN_; i++) {
        acc += hs_f(X[xbase + (size_t)i * C_] * inv1[rbase + i] * wgt);
        state[(size_t)(rbase + i) * C_ + c] = (bf16_t)acc;
    }
    csum[(size_t)bch * C_ + c] = acc;
}

__global__ __launch_bounds__(256) void scan_offsets_hilo(const float* __restrict__ csum,
                                                         bf16_t* __restrict__ hilo) {
    const int idx = blockIdx.x * 256 + threadIdx.x;   // b*1024 + c
    const int b = idx >> 10, c = idx & 1023;
    const size_t base = (size_t)b * NCH_ * C_ + c;
    float v[NCH_];
    #pragma unroll
    for (int ch = 0; ch < NCH_; ch++)
        v[ch] = csum[base + (size_t)ch * C_];
    float run = 0.0f;
    #pragma unroll
    for (int ch = 0; ch < NCH_; ch++) {
        const size_t row = (size_t)(b * NCH_ + ch) * 2048 + c;
        const bf16_t hi = (bf16_t)run;
        hilo[row] = hi;
        hilo[row + 1024] = (bf16_t)(run - (float)hi);
        run += v[ch];
    }
}

// ---------------------------------------------------------------------------
// All 3 weight transposes + Pmat seed + rs2 zero in ONE launch (R12 merge).
// Blocks [0,9216): transposes (R10 layout). Blocks [9216,10240): flat init —
// Pmat[i] = b1[i&1023] over 256x1024, rs2[i] = 0 over BT.
// ---------------------------------------------------------------------------
__global__ __launch_bounds__(256) void transpose_all(const float* __restrict__ w1,
                                                     const float* __restrict__ w2a,
                                                     const float* __restrict__ w2b,
                                                     const float* __restrict__ n2w,
                                                     const float* __restrict__ b1,
                                                     bf16_t* __restrict__ W1cat,
                                                     bf16_t* __restrict__ W2at,
                                                     bf16_t* __restrict__ W2bt,
                                                     float* __restrict__ Pmat,
                                                     float* __restrict__ rs2) {
    const int flat = blockIdx.x;
    if (flat >= 9216) {                      // init tail
        const int i = (flat - 9216) * 256 + threadIdx.x;
        Pmat[i] = b1[i & (C_ - 1)];
        if (i < BT_) rs2[i] = 0.0f;
        return;
    }
    __shared__ float tile[32][33];
    const float* src; bf16_t* dst; const float* scale;
    int N, ldd, dupOff, bx, by;
    if (flat < 1024) {          // w1 -> W1cat: K=C,N=C, ldd=2048, dup
        src = w1; dst = W1cat; scale = nullptr;
        N = C_; ldd = 2048; dupOff = 1024;
        bx = flat & 31; by = flat >> 5;               // 32 x 32
    } else if (flat < 5120) {   // w2a -> W2at: K=C,N=H, ldd=C, scale=n2w
        const int f = flat - 1024;
        src = w2a; dst = W2at; scale = n2w;
        N = H_; ldd = C_; dupOff = 0;
        bx = f & 127; by = f >> 7;                    // 128 x 32
    } else {                    // w2b -> W2bt: K=H,N=C, ldd=H
        const int f = flat - 5120;
        src = w2b; dst = W2bt; scale = nullptr;
        N = C_; ldd = H_; dupOff = 0;
        bx = f & 31; by = f >> 5;                     // 32 x 128
    }
    const int n0 = bx * 32, k0 = by * 32;
    const int tx = threadIdx.x & 31, ty = threadIdx.x >> 5;
    #pragma unroll
    for (int j = 0; j < 4; j++) {
        const int kk = ty + j * 8;
        float v = src[(size_t)(k0 + kk) * N + n0 + tx];
        if (scale) v *= scale[k0 + kk];
        tile[kk][tx] = v;
    }
    __syncthreads();
    #pragma unroll
    for (int j = 0; j < 4; j++) {
        const int nn = ty + j * 8;
        const bf16_t v = (bf16_t)tile[tx][nn];
        dst[(size_t)(n0 + nn) * ldd + k0 + tx] = v;
        if (dupOff) dst[(size_t)(n0 + nn) * ldd + dupOff + k0 + tx] = v;
    }
}

// ---------------------------------------------------------------------------
// 128x128 2-deep pipelined GEMM (R8/R11-verified) — ONLY for split-K P-GEMM.
// ---------------------------------------------------------------------------
__global__ __launch_bounds__(256) void gemm_pk(const bf16_t* __restrict__ A,
                                               const bf16_t* __restrict__ Bt,
                                               float* __restrict__ Cmat,
                                               int N, int K, int lda, int ldb) {
    __shared__ __align__(16) bf16_t As[2][128 * 32];
    __shared__ __align__(16) bf16_t Bs[2][128 * 32];
    const int tid = threadIdx.x;
    const int mBase = blockIdx.x * 128;
    const int nBase = blockIdx.y * 128;
    const size_t kOff = (size_t)blockIdx.z * K;

    const int wave = tid >> 6;
    const int lane = tid & 63;
    const int waveM = (wave & 1) * 64;
    const int waveN = (wave >> 1) * 64;
    const int lr = lane & 15;
    const int lq = lane >> 4;

    f32x4 acc[4][4] = {};

    const int e0 = tid * 8;
    const int r0 = e0 >> 5, c0 = (((e0 >> 3) & 3) ^ ((r0 >> 1) & 3)) << 3;
    const int e1 = 2048 + tid * 8;
    const int r1 = e1 >> 5, c1 = (((e1 >> 3) & 3) ^ ((r1 >> 1) & 3)) << 3;

    const bf16_t* Ag0 = A + (size_t)(mBase + r0) * lda + kOff + c0;
    const bf16_t* Ag1 = A + (size_t)(mBase + r1) * lda + kOff + c1;
    const bf16_t* Bg0 = Bt + (size_t)(nBase + r0) * ldb + kOff + c0;
    const bf16_t* Bg1 = Bt + (size_t)(nBase + r1) * ldb + kOff + c1;

    auto stage = [&](int buf, int kb) {
        gld_lds16(Ag0 + kb, As[buf] + e0);
        gld_lds16(Ag1 + kb, As[buf] + e1);
        gld_lds16(Bg0 + kb, Bs[buf] + e0);
        gld_lds16(Bg1 + kb, Bs[buf] + e1);
    };

    stage(0, 0);
    if (32 < K) stage(1, 32);

    int cur = 0;
    for (int kb = 0; kb < K; kb += 32) {
        if (kb + 32 < K) asm volatile("s_waitcnt vmcnt(4)" ::: "memory");
        else             asm volatile("s_waitcnt vmcnt(0)" ::: "memory");
        __builtin_amdgcn_s_barrier();

        bf16x8 af[4], bfr[4];
        #pragma unroll
        for (int mi = 0; mi < 4; mi++) {
            const int R = waveM + mi * 16 + lr;
            af[mi] = *(const bf16x8*)(As[cur] + R * 32 + ((lq ^ ((R >> 1) & 3)) << 3));
        }
        #pragma unroll
        for (int ni = 0; ni < 4; ni++) {
            const int R = waveN + ni * 16 + lr;
            bfr[ni] = *(const bf16x8*)(Bs[cur] + R * 32 + ((lq ^ ((R >> 1) & 3)) << 3));
        }
        #pragma unroll
        for (int mi = 0; mi < 4; mi++)
            #pragma unroll
            for (int ni = 0; ni < 4; ni++)
                acc[mi][ni] = __builtin_amdgcn_mfma_f32_16x16x32_bf16(
                    af[mi], bfr[ni], acc[mi][ni], 0, 0, 0);

        __builtin_amdgcn_s_barrier();
        if (kb + 64 < K) stage(cur, kb + 64);
        cur ^= 1;
    }

    #pragma unroll
    for (int ni = 0; ni < 4; ni++) {
        const int n = nBase + waveN + ni * 16 + lr;
        #pragma unroll
        for (int mi = 0; mi < 4; mi++) {
            #pragma unroll
            for (int r = 0; r < 4; r++) {
                const int m = mBase + waveM + mi * 16 + lq * 4 + r;
                atomicAdd(&Cmat[(size_t)m * N + n], acc[mi][ni][r]);
            }
        }
    }
}

// ---------------------------------------------------------------------------
// 256x128 2-deep pipelined GEMM (R12): 512 thr = 8 waves as 4M x 2N, each
// wave 64x64 — the per-wave inner pattern (4+4 ds_read_b128, 16 MFMA, 64-VGPR
// acc) is BYTE-IDENTICAL to the verified R11 kernel, so VGPR stays ~108 and
// waves/CU stays 16 (the R9/R10 failures dropped waves; this doesn't).
// Gains: barriers amortize over 2x block FLOPs; staging 3 loads/thread
// (A 2 + B 1, was 4); LDS 48 KB -> 2 blocks/CU.
//
// Pipeline (T4, R8-verified invariant, now 3-load stages):
//   prologue: STAGE(buf0,k0); STAGE(buf1,k0+32)    [6 in flight]
//   iter t:   vmcnt(3|0) -> s_barrier -> ds_read+MFMA(buf t&1) -> s_barrier
//             -> STAGE(buf t&1, kb+64)
// Swizzle (T2, R6-verified): phys slot s' = s ^ ((row>>1)&3); LDS dest
// linear, global source pre-swizzled, ds_read same XOR (rule #21).
// Ascending-K 32-groups -> bitwise-same numerics.
//
// MODE 0: out bf16 = hs(acc + pmat[(m>>6)*N+n]) * xf32[m*N+n]; + fused row
//         sum-of-squares of bf16-rounded out into aux[m] (atomicAdd).
// MODE 1: out bf16 = relu(rsqrt(rs2[m]/C+eps)*acc + bias[n])  (GEMM2a;
//         rowscale param = rs2, inv computed inline == old inv_finish).
// MODE 2: out f32  = acc + bias[n] + (f32)extra_bf16[m*N+n]   (GEMM2b)
// ---------------------------------------------------------------------------
template <int MODE, typename ET, typename OT>
__global__ __launch_bounds__(512) void gemm_bt(const bf16_t* __restrict__ A,
                                               const bf16_t* __restrict__ Bt,
                                               const float* __restrict__ bias,
                                               const ET* __restrict__ extra,
                                               const float* __restrict__ rowscale,
                                               const float* __restrict__ pmat,
                                               float* __restrict__ aux,
                                               OT* __restrict__ Cmat,
                                               int N, int K, int lda, int ldb) {
    __shared__ __align__(16) bf16_t As[2][256 * 32];   // 2 x 16 KB
    __shared__ __align__(16) bf16_t Bs[2][128 * 32];   // 2 x  8 KB
    const int tid = threadIdx.x;

    const int nwgx = gridDim.x;
    const int flat0 = blockIdx.y * nwgx + blockIdx.x;
    int mTile, nTile;
    if ((nwgx & 7) == 0) {                  // XCD m-slice mapping (R3 win)
        const int xcd = flat0 & 7;
        const int loc = flat0 >> 3;
        const int mpx = nwgx >> 3;
        mTile = xcd * mpx + (loc % mpx);
        nTile = loc / mpx;
    } else {
        mTile = blockIdx.x;
        nTile = blockIdx.y;
    }
    const int mBase = mTile * 256;
    const int nBase = nTile * 128;

    const int wave = tid >> 6;
    const int lane = tid & 63;
    const int waveM = (wave >> 1) * 64;     // 4 M-quarters
    const int waveN = (wave & 1) * 64;      // 2 N-halves
    const int lr = lane & 15;
    const int lq = lane >> 4;

    f32x4 acc[4][4] = {};

    // Staging: A = 2 x 16B/thread (rows 0..255), B = 1 x 16B (rows 0..127).
    // Element e -> row e>>5, phys slot (e>>3)&3; source col pre-swizzled.
    const int a0 = tid * 8;
    const int ar0 = a0 >> 5, ac0 = (((a0 >> 3) & 3) ^ ((ar0 >> 1) & 3)) << 3;
    const int a1 = 4096 + tid * 8;
    const int ar1 = a1 >> 5, ac1 = (((a1 >> 3) & 3) ^ ((ar1 >> 1) & 3)) << 3;
    const int b0 = tid * 8;
    const int br0 = b0 >> 5, bc0 = (((b0 >> 3) & 3) ^ ((br0 >> 1) & 3)) << 3;

    const bf16_t* Ag0 = A + (size_t)(mBase + ar0) * lda + ac0;
    const bf16_t* Ag1 = A + (size_t)(mBase + ar1) * lda + ac1;
    const bf16_t* Bg0 = Bt + (size_t)(nBase + br0) * ldb + bc0;

    auto stage = [&](int buf, int kb) {
        gld_lds16(Ag0 + kb, As[buf] + a0);
        gld_lds16(Ag1 + kb, As[buf] + a1);
        gld_lds16(Bg0 + kb, Bs[buf] + b0);
    };

    stage(0, 0);
    if (32 < K) stage(1, 32);

    int cur = 0;
    for (int kb = 0; kb < K; kb += 32) {
        if (kb + 32 < K) asm volatile("s_waitcnt vmcnt(3)" ::: "memory");
        else             asm volatile("s_waitcnt vmcnt(0)" ::: "memory");
        __builtin_amdgcn_s_barrier();       // buf cur staged for all waves

        bf16x8 af[4], bfr[4];
        #pragma unroll
        for (int mi = 0; mi < 4; mi++) {
            const int R = waveM + mi * 16 + lr;
            af[mi] = *(const bf16x8*)(As[cur] + R * 32 + ((lq ^ ((R >> 1) & 3)) << 3));
        }
        #pragma unroll
        for (int ni = 0; ni < 4; ni++) {
            const int R = waveN + ni * 16 + lr;
            bfr[ni] = *(const bf16x8*)(Bs[cur] + R * 32 + ((lq ^ ((R >> 1) & 3)) << 3));
        }
        #pragma unroll
        for (int mi = 0; mi < 4; mi++)
            #pragma unroll
            for (int ni = 0; ni < 4; ni++)
                acc[mi][ni] = __builtin_amdgcn_mfma_f32_16x16x32_bf16(
                    af[mi], bfr[ni], acc[mi][ni], 0, 0, 0);

        __builtin_amdgcn_s_barrier();       // all waves done reading buf cur
        if (kb + 64 < K) stage(cur, kb + 64);
        cur ^= 1;
    }

    // Epilogue. C/D layout: col(n)=lane&15, row(m)=(lane>>4)*4+reg.
    float sq[4][4];                          // MODE 0: per-(mi,r) sum v^2
    float invm[4][4];                        // MODE 1: inline inv_finish
    if (MODE == 0) {
        #pragma unroll
        for (int a = 0; a < 4; a++)
            #pragma unroll
            for (int b = 0; b < 4; b++) sq[a][b] = 0.0f;
    }
    if (MODE == 1) {
        #pragma unroll
        for (int mi = 0; mi < 4; mi++)
            #pragma unroll
            for (int r = 0; r < 4; r++) {
                const int m = mBase + waveM + mi * 16 + lq * 4 + r;
                invm[mi][r] = rsqrtf(rowscale[m] * (1.0f / C_) + 1e-6f);
            }
    }
    #pragma unroll
    for (int ni = 0; ni < 4; ni++) {
        const int n = nBase + waveN + ni * 16 + lr;
        const float bz = (MODE == 1 || MODE == 2) ? bias[n] : 0.0f;
        #pragma unroll
        for (int mi = 0; mi < 4; mi++) {
            #pragma unroll
            for (int r = 0; r < 4; r++) {
                const int m = mBase + waveM + mi * 16 + lq * 4 + r;
                float v = acc[mi][ni][r];
                if (MODE == 0) {
                    v = hs_f(v + pmat[(size_t)(m >> 6) * N + n]) * (float)extra[(size_t)m * N + n];
                    const OT vs = (OT)v;
                    Cmat[(size_t)m * N + n] = vs;
                    const float vb = (float)vs;      // bf16-rounded, matches old pass
                    sq[mi][r] += vb * vb;
                } else if (MODE == 1) {
                    v = fmaxf(invm[mi][r] * v + bz, 0.0f);
                    Cmat[(size_t)m * N + n] = (OT)v;
                } else {
                    v = v + bz + (float)extra[(size_t)m * N + n];
                    Cmat[(size_t)m * N + n] = (OT)v;
                }
            }
        }
    }
    if (MODE == 0) {
        #pragma unroll
        for (int mi = 0; mi < 4; mi++) {
            #pragma unroll
            for (int r = 0; r < 4; r++) {
                float s = sq[mi][r];
                s += __shfl_xor(s, 1, 64);
                s += __shfl_xor(s, 2, 64);
                s += __shfl_xor(s, 4, 64);
                s += __shfl_xor(s, 8, 64);
                if (lr == 0) {
                    const int m = mBase + waveM + mi * 16 + lq * 4 + r;
                    atomicAdd(&aux[m], s);
                }
            }
        }
    }
}

// ---------------------------------------------------------------------------
extern "C" void kernel_launch(void* const* d_in, const int* in_sizes, int n_in,
                              void* d_out, int out_size, void* d_ws, size_t ws_size,
                              hipStream_t stream) {
    const float* x   = (const float*)d_in[0];
    const float* n1w = (const float*)d_in[1];
    const float* w1  = (const float*)d_in[2];
    const float* b1  = (const float*)d_in[3];
    const float* n2w = (const float*)d_in[4];
    const float* w2a = (const float*)d_in[5];
    const float* b2a = (const float*)d_in[6];
    const float* w2b = (const float*)d_in[7];
    const float* b2b = (const float*)d_in[8];
    float* y = (float*)d_out;

    char* w = (char*)d_ws;
    float*  inv1  = (float*)(w + 0);
    float*  csum  = (float*)(w + 131072);    // also rs2 after scan (64KB head)
    bf16_t* hilo  = (bf16_t*)(w + 1179648);
    float*  Pmat  = (float*)(w + 2228224);
    bf16_t* W1cat = (bf16_t*)(w + 5373952);
    bf16_t* W2at  = (bf16_t*)(w + 9568256);
    bf16_t* W2bt  = (bf16_t*)(w + 17956864);
    bf16_t* outb  = (bf16_t*)(w + 26345472);
    bf16_t* state = (bf16_t*)(w + 59899904);
    bf16_t* hbuf  = state;
    float*  rs2   = csum;                    // csum dead after scan_offsets_hilo

    rms_rows_f32<<<dim3(BT_ / 4), dim3(256), 0, stream>>>(x, inv1);
    scan_emit_local<<<dim3(B_ * NCH_, C_ / 256), dim3(256), 0, stream>>>(x, inv1, n1w, state, csum);
    scan_offsets_hilo<<<dim3(B_ * C_ / 256), dim3(256), 0, stream>>>(csum, hilo);
    // transposes + Pmat seed + rs2 zero, one launch
    transpose_all<<<dim3(10240), dim3(256), 0, stream>>>(
        w1, w2a, w2b, n2w, b1, W1cat, W2at, W2bt, Pmat, rs2);
    gemm_pk<<<dim3(2, C_ / 128, 4), dim3(256), 0, stream>>>(
        hilo, W1cat, Pmat, C_, 512, 2048, 2048);
    // GEMM1: M=16384, N=1024, K=1024 -> 64x8 = 512 blocks (+fused rms sumsq)
    gemm_bt<0, float, bf16_t><<<dim3(BT_ / 256, C_ / 128), dim3(512), 0, stream>>>(
        state, W1cat, nullptr, x, nullptr, Pmat, rs2, outb, C_, C_, C_, 2048);
    for (int c = 0; c < BT_ / MCHUNK; c++) {
        const bf16_t* Ao = outb + (size_t)c * MCHUNK * C_;
        float* yo = y + (size_t)c * MCHUNK * C_;
        // GEMM2a: M=8192, N=4096, K=1024 -> 32x32 = 1024 blocks (inline inv)
        gemm_bt<1, float, bf16_t><<<dim3(MCHUNK / 256, H_ / 128), dim3(512), 0, stream>>>(
            Ao, W2at, b2a, nullptr, rs2 + c * MCHUNK, nullptr, nullptr, hbuf, H_, C_, C_, C_);
        // GEMM2b: M=8192, N=1024, K=4096 -> 32x8 = 256 blocks
        gemm_bt<2, bf16_t, float><<<dim3(MCHUNK / 256, C_ / 128), dim3(512), 0, stream>>>(
            hbuf, W2bt, b2b, Ao, nullptr, nullptr, nullptr, yo, C_, H_, H_, H_);
    }
}

// Round 13
// 576.996 us; speedup vs baseline: 1.0657x; 1.0657x over previous
//
#include <hip/hip_runtime.h>

#define B_     4
#define T_     4096
#define C_     1024
#define H_     4096
#define BT_    (B_ * T_)
#define NCH_   64
#define CHLEN_ 64
#define MCHUNK 8192   // rows per h-chunk for GEMM2a/2b (2 chunks)

typedef __bf16 bf16_t;
typedef __bf16 bf16x8 __attribute__((ext_vector_type(8)));
typedef float  f32x4  __attribute__((ext_vector_type(4)));

__device__ __forceinline__ float hs_f(float v) {
    return fminf(fmaxf((v + 3.0f) * (1.0f / 6.0f), 0.0f), 1.0f) - 0.5f;
}

__device__ __forceinline__ void gld_lds16(const bf16_t* g, bf16_t* l) {
    __builtin_amdgcn_global_load_lds((const __attribute__((address_space(1))) void*)g,
                                     (__attribute__((address_space(3))) void*)l,
                                     16, 0, 0);
}

// ---------------------------------------------------------------------------
__global__ __launch_bounds__(256) void rms_rows_f32(const float* __restrict__ X,
                                                    float* __restrict__ inv) {
    const int wave = threadIdx.x >> 6, lane = threadIdx.x & 63;
    const int row = blockIdx.x * 4 + wave;
    const float* xr = X + (size_t)row * C_;
    float s = 0.0f;
    #pragma unroll
    for (int p = 0; p < 4; p++) {
        float4 v = *(const float4*)(xr + p * 256 + lane * 4);
        s += v.x * v.x + v.y * v.y + v.z * v.z + v.w * v.w;
    }
    #pragma unroll
    for (int o = 32; o > 0; o >>= 1) s += __shfl_down(s, o, 64);
    if (lane == 0) inv[row] = rsqrtf(s * (1.0f / C_) + 1e-6f);
}

// ---------------------------------------------------------------------------
__global__ __launch_bounds__(256) void scan_emit_local(const float* __restrict__ X,
                                                       const float* __restrict__ inv1,
                                                       const float* __restrict__ nw,
                                                       bf16_t* __restrict__ state,
                                                       float* __restrict__ csum) {
    const int bch = blockIdx.x;
    const int b = bch >> 6, ch = bch & 63;
    const int c = blockIdx.y * 256 + threadIdx.x;
    const float wgt = nw[c];
    const int rbase = b * T_ + ch * CHLEN_;
    const size_t xbase = (size_t)rbase * C_ + c;
    float acc = 0.0f;
    for (int i = 0; i < CHLEN_; i++) {
        acc += hs_f(X[xbase + (size_t)i * C_] * inv1[rbase + i] * wgt);
        state[(size_t)(rbase + i) * C_ + c] = (bf16_t)acc;
    }
    csum[(size_t)bch * C_ + c] = acc;
}

__global__ __launch_bounds__(256) void scan_offsets_hilo(const float* __restrict__ csum,
                                                         bf16_t* __restrict__ hilo) {
    const int idx = blockIdx.x * 256 + threadIdx.x;   // b*1024 + c
    const int b = idx >> 10, c = idx & 1023;
    const size_t base = (size_t)b * NCH_ * C_ + c;
    float v[NCH_];
    #pragma unroll
    for (int ch = 0; ch < NCH_; ch++)
        v[ch] = csum[base + (size_t)ch * C_];
    float run = 0.0f;
    #pragma unroll
    for (int ch = 0; ch < NCH_; ch++) {
        const size_t row = (size_t)(b * NCH_ + ch) * 2048 + c;
        const bf16_t hi = (bf16_t)run;
        hilo[row] = hi;
        hilo[row + 1024] = (bf16_t)(run - (float)hi);
        run += v[ch];
    }
}

// ---------------------------------------------------------------------------
// All 3 weight transposes + Pmat seed + rs2 zero in ONE launch (R12 merge).
// ---------------------------------------------------------------------------
__global__ __launch_bounds__(256) void transpose_all(const float* __restrict__ w1,
                                                     const float* __restrict__ w2a,
                                                     const float* __restrict__ w2b,
                                                     const float* __restrict__ n2w,
                                                     const float* __restrict__ b1,
                                                     bf16_t* __restrict__ W1cat,
                                                     bf16_t* __restrict__ W2at,
                                                     bf16_t* __restrict__ W2bt,
                                                     float* __restrict__ Pmat,
                                                     float* __restrict__ rs2) {
    const int flat = blockIdx.x;
    if (flat >= 9216) {                      // init tail
        const int i = (flat - 9216) * 256 + threadIdx.x;
        Pmat[i] = b1[i & (C_ - 1)];
        if (i < BT_) rs2[i] = 0.0f;
        return;
    }
    __shared__ float tile[32][33];
    const float* src; bf16_t* dst; const float* scale;
    int N, ldd, dupOff, bx, by;
    if (flat < 1024) {          // w1 -> W1cat: K=C,N=C, ldd=2048, dup
        src = w1; dst = W1cat; scale = nullptr;
        N = C_; ldd = 2048; dupOff = 1024;
        bx = flat & 31; by = flat >> 5;               // 32 x 32
    } else if (flat < 5120) {   // w2a -> W2at: K=C,N=H, ldd=C, scale=n2w
        const int f = flat - 1024;
        src = w2a; dst = W2at; scale = n2w;
        N = H_; ldd = C_; dupOff = 0;
        bx = f & 127; by = f >> 7;                    // 128 x 32
    } else {                    // w2b -> W2bt: K=H,N=C, ldd=H
        const int f = flat - 5120;
        src = w2b; dst = W2bt; scale = nullptr;
        N = C_; ldd = H_; dupOff = 0;
        bx = f & 31; by = f >> 5;                     // 32 x 128
    }
    const int n0 = bx * 32, k0 = by * 32;
    const int tx = threadIdx.x & 31, ty = threadIdx.x >> 5;
    #pragma unroll
    for (int j = 0; j < 4; j++) {
        const int kk = ty + j * 8;
        float v = src[(size_t)(k0 + kk) * N + n0 + tx];
        if (scale) v *= scale[k0 + kk];
        tile[kk][tx] = v;
    }
    __syncthreads();
    #pragma unroll
    for (int j = 0; j < 4; j++) {
        const int nn = ty + j * 8;
        const bf16_t v = (bf16_t)tile[tx][nn];
        dst[(size_t)(n0 + nn) * ldd + k0 + tx] = v;
        if (dupOff) dst[(size_t)(n0 + nn) * ldd + dupOff + k0 + tx] = v;
    }
}

// ---------------------------------------------------------------------------
// 128x128 2-deep pipelined GEMM, 256 thr (R8/R11-verified: VGPR=108,
// 16 waves/CU, no spill). MODE 2: GEMM2b (f32 out = acc+bias+extra).
// MODE 4: split-K P-GEMM (atomicAdd). R13: GEMM2b moved BACK here from the
// 512-thr kernel — R12 PMC showed the 512-thr default heuristic spilled
// (VGPR=60 < acc's 64) and its 256-block grid gave only 1 block/CU.
// ---------------------------------------------------------------------------
template <int MODE, typename ET, typename OT>
__global__ __launch_bounds__(256) void gemm128(const bf16_t* __restrict__ A,
                                               const bf16_t* __restrict__ Bt,
                                               const float* __restrict__ bias,
                                               const ET* __restrict__ extra,
                                               OT* __restrict__ Cmat,
                                               int N, int K, int lda, int ldb) {
    __shared__ __align__(16) bf16_t As[2][128 * 32];
    __shared__ __align__(16) bf16_t Bs[2][128 * 32];
    const int tid = threadIdx.x;

    const int nwgx = gridDim.x;
    const int flat0 = blockIdx.y * nwgx + blockIdx.x;
    int mTile, nTile;
    if ((nwgx & 7) == 0) {                  // XCD m-slice mapping (R3 win)
        const int xcd = flat0 & 7;
        const int loc = flat0 >> 3;
        const int mpx = nwgx >> 3;
        mTile = xcd * mpx + (loc % mpx);
        nTile = loc / mpx;
    } else {
        mTile = blockIdx.x;
        nTile = blockIdx.y;
    }
    const int mBase = mTile * 128;
    const int nBase = nTile * 128;
    const size_t kOff = (size_t)blockIdx.z * K;

    const int wave = tid >> 6;
    const int lane = tid & 63;
    const int waveM = (wave & 1) * 64;
    const int waveN = (wave >> 1) * 64;
    const int lr = lane & 15;
    const int lq = lane >> 4;

    f32x4 acc[4][4] = {};

    const int e0 = tid * 8;
    const int r0 = e0 >> 5, c0 = (((e0 >> 3) & 3) ^ ((r0 >> 1) & 3)) << 3;
    const int e1 = 2048 + tid * 8;
    const int r1 = e1 >> 5, c1 = (((e1 >> 3) & 3) ^ ((r1 >> 1) & 3)) << 3;

    const bf16_t* Ag0 = A + (size_t)(mBase + r0) * lda + kOff + c0;
    const bf16_t* Ag1 = A + (size_t)(mBase + r1) * lda + kOff + c1;
    const bf16_t* Bg0 = Bt + (size_t)(nBase + r0) * ldb + kOff + c0;
    const bf16_t* Bg1 = Bt + (size_t)(nBase + r1) * ldb + kOff + c1;

    auto stage = [&](int buf, int kb) {
        gld_lds16(Ag0 + kb, As[buf] + e0);
        gld_lds16(Ag1 + kb, As[buf] + e1);
        gld_lds16(Bg0 + kb, Bs[buf] + e0);
        gld_lds16(Bg1 + kb, Bs[buf] + e1);
    };

    stage(0, 0);
    if (32 < K) stage(1, 32);

    int cur = 0;
    for (int kb = 0; kb < K; kb += 32) {
        if (kb + 32 < K) asm volatile("s_waitcnt vmcnt(4)" ::: "memory");
        else             asm volatile("s_waitcnt vmcnt(0)" ::: "memory");
        __builtin_amdgcn_s_barrier();

        bf16x8 af[4], bfr[4];
        #pragma unroll
        for (int mi = 0; mi < 4; mi++) {
            const int R = waveM + mi * 16 + lr;
            af[mi] = *(const bf16x8*)(As[cur] + R * 32 + ((lq ^ ((R >> 1) & 3)) << 3));
        }
        #pragma unroll
        for (int ni = 0; ni < 4; ni++) {
            const int R = waveN + ni * 16 + lr;
            bfr[ni] = *(const bf16x8*)(Bs[cur] + R * 32 + ((lq ^ ((R >> 1) & 3)) << 3));
        }
        #pragma unroll
        for (int mi = 0; mi < 4; mi++)
            #pragma unroll
            for (int ni = 0; ni < 4; ni++)
                acc[mi][ni] = __builtin_amdgcn_mfma_f32_16x16x32_bf16(
                    af[mi], bfr[ni], acc[mi][ni], 0, 0, 0);

        __builtin_amdgcn_s_barrier();
        if (kb + 64 < K) stage(cur, kb + 64);
        cur ^= 1;
    }

    #pragma unroll
    for (int ni = 0; ni < 4; ni++) {
        const int n = nBase + waveN + ni * 16 + lr;
        const float bz = (MODE == 2) ? bias[n] : 0.0f;
        #pragma unroll
        for (int mi = 0; mi < 4; mi++) {
            #pragma unroll
            for (int r = 0; r < 4; r++) {
                const int m = mBase + waveM + mi * 16 + lq * 4 + r;
                float v = acc[mi][ni][r];
                if (MODE == 2) {
                    v = v + bz + (float)extra[(size_t)m * N + n];
                    Cmat[(size_t)m * N + n] = (OT)v;
                } else {
                    atomicAdd((float*)&Cmat[(size_t)m * N + n], v);
                }
            }
        }
    }
}

// ---------------------------------------------------------------------------
// 256x128 2-deep pipelined GEMM, 512 thr = 8 waves (4M x 2N), per-wave 64x64
// (inner pattern identical to gemm128). R13 fix: __launch_bounds__(512, 4)
// caps VGPR at 128 >= natural ~108 -> allocator keeps acc in registers.
// R12 PMC: default heuristic picked VGPR=60 (< acc's 64) and spilled
// (FETCH 77 vs 72 ideal, WRITE 45 vs 33). Cap-above-natural removes the bad
// heuristic; cap-below-natural (R10, 102<108) forces spill — the distinction.
// 2 blocks/CU x 8 waves = 16 waves/CU, same as gemm128.
//
// Pipeline: prologue STAGE(buf0,k0)+STAGE(buf1,k0+32) [3 loads each];
// iter: vmcnt(3|0) -> s_barrier -> ds_read+MFMA -> s_barrier -> STAGE(kb+64).
// Swizzle (T2): phys slot s' = s ^ ((row>>1)&3), both-sides (rule #21).
//
// MODE 0: out bf16 = hs(acc + pmat[(m>>6)*N+n]) * xf32[m*N+n]; + fused row
//         sum-of-squares of bf16-rounded out into aux[m] (atomicAdd).
// MODE 1: out bf16 = relu(rsqrt(rs2[m]/C+eps)*acc + bias[n])  (GEMM2a)
// ---------------------------------------------------------------------------
template <int MODE, typename ET, typename OT>
__global__ __launch_bounds__(512, 4) void gemm_bt(const bf16_t* __restrict__ A,
                                                  const bf16_t* __restrict__ Bt,
                                                  const float* __restrict__ bias,
                                                  const ET* __restrict__ extra,
                                                  const float* __restrict__ rowscale,
                                                  const float* __restrict__ pmat,
                                                  float* __restrict__ aux,
                                                  OT* __restrict__ Cmat,
                                                  int N, int K, int lda, int ldb) {
    __shared__ __align__(16) bf16_t As[2][256 * 32];   // 2 x 16 KB
    __shared__ __align__(16) bf16_t Bs[2][128 * 32];   // 2 x  8 KB
    const int tid = threadIdx.x;

    const int nwgx = gridDim.x;
    const int flat0 = blockIdx.y * nwgx + blockIdx.x;
    int mTile, nTile;
    if ((nwgx & 7) == 0) {                  // XCD m-slice mapping (R3 win)
        const int xcd = flat0 & 7;
        const int loc = flat0 >> 3;
        const int mpx = nwgx >> 3;
        mTile = xcd * mpx + (loc % mpx);
        nTile = loc / mpx;
    } else {
        mTile = blockIdx.x;
        nTile = blockIdx.y;
    }
    const int mBase = mTile * 256;
    const int nBase = nTile * 128;

    const int wave = tid >> 6;
    const int lane = tid & 63;
    const int waveM = (wave >> 1) * 64;     // 4 M-quarters
    const int waveN = (wave & 1) * 64;      // 2 N-halves
    const int lr = lane & 15;
    const int lq = lane >> 4;

    f32x4 acc[4][4] = {};

    const int a0 = tid * 8;
    const int ar0 = a0 >> 5, ac0 = (((a0 >> 3) & 3) ^ ((ar0 >> 1) & 3)) << 3;
    const int a1 = 4096 + tid * 8;
    const int ar1 = a1 >> 5, ac1 = (((a1 >> 3) & 3) ^ ((ar1 >> 1) & 3)) << 3;
    const int b0 = tid * 8;
    const int br0 = b0 >> 5, bc0 = (((b0 >> 3) & 3) ^ ((br0 >> 1) & 3)) << 3;

    const bf16_t* Ag0 = A + (size_t)(mBase + ar0) * lda + ac0;
    const bf16_t* Ag1 = A + (size_t)(mBase + ar1) * lda + ac1;
    const bf16_t* Bg0 = Bt + (size_t)(nBase + br0) * ldb + bc0;

    auto stage = [&](int buf, int kb) {
        gld_lds16(Ag0 + kb, As[buf] + a0);
        gld_lds16(Ag1 + kb, As[buf] + a1);
        gld_lds16(Bg0 + kb, Bs[buf] + b0);
    };

    stage(0, 0);
    if (32 < K) stage(1, 32);

    int cur = 0;
    for (int kb = 0; kb < K; kb += 32) {
        if (kb + 32 < K) asm volatile("s_waitcnt vmcnt(3)" ::: "memory");
        else             asm volatile("s_waitcnt vmcnt(0)" ::: "memory");
        __builtin_amdgcn_s_barrier();       // buf cur staged for all waves

        bf16x8 af[4], bfr[4];
        #pragma unroll
        for (int mi = 0; mi < 4; mi++) {
            const int R = waveM + mi * 16 + lr;
            af[mi] = *(const bf16x8*)(As[cur] + R * 32 + ((lq ^ ((R >> 1) & 3)) << 3));
        }
        #pragma unroll
        for (int ni = 0; ni < 4; ni++) {
            const int R = waveN + ni * 16 + lr;
            bfr[ni] = *(const bf16x8*)(Bs[cur] + R * 32 + ((lq ^ ((R >> 1) & 3)) << 3));
        }
        #pragma unroll
        for (int mi = 0; mi < 4; mi++)
            #pragma unroll
            for (int ni = 0; ni < 4; ni++)
                acc[mi][ni] = __builtin_amdgcn_mfma_f32_16x16x32_bf16(
                    af[mi], bfr[ni], acc[mi][ni], 0, 0, 0);

        __builtin_amdgcn_s_barrier();       // all waves done reading buf cur
        if (kb + 64 < K) stage(cur, kb + 64);
        cur ^= 1;
    }

    // Epilogue. C/D layout: col(n)=lane&15, row(m)=(lane>>4)*4+reg.
    float sq[4][4];                          // MODE 0: per-(mi,r) sum v^2
    float invm[4][4];                        // MODE 1: inline inv_finish
    if (MODE == 0) {
        #pragma unroll
        for (int a = 0; a < 4; a++)
            #pragma unroll
            for (int b = 0; b < 4; b++) sq[a][b] = 0.0f;
    }
    if (MODE == 1) {
        #pragma unroll
        for (int mi = 0; mi < 4; mi++)
            #pragma unroll
            for (int r = 0; r < 4; r++) {
                const int m = mBase + waveM + mi * 16 + lq * 4 + r;
                invm[mi][r] = rsqrtf(rowscale[m] * (1.0f / C_) + 1e-6f);
            }
    }
    #pragma unroll
    for (int ni = 0; ni < 4; ni++) {
        const int n = nBase + waveN + ni * 16 + lr;
        const float bz = (MODE == 1) ? bias[n] : 0.0f;
        #pragma unroll
        for (int mi = 0; mi < 4; mi++) {
            #pragma unroll
            for (int r = 0; r < 4; r++) {
                const int m = mBase + waveM + mi * 16 + lq * 4 + r;
                float v = acc[mi][ni][r];
                if (MODE == 0) {
                    v = hs_f(v + pmat[(size_t)(m >> 6) * N + n]) * (float)extra[(size_t)m * N + n];
                    const OT vs = (OT)v;
                    Cmat[(size_t)m * N + n] = vs;
                    const float vb = (float)vs;      // bf16-rounded, matches old pass
                    sq[mi][r] += vb * vb;
                } else {
                    v = fmaxf(invm[mi][r] * v + bz, 0.0f);
                    Cmat[(size_t)m * N + n] = (OT)v;
                }
            }
        }
    }
    if (MODE == 0) {
        #pragma unroll
        for (int mi = 0; mi < 4; mi++) {
            #pragma unroll
            for (int r = 0; r < 4; r++) {
                float s = sq[mi][r];
                s += __shfl_xor(s, 1, 64);
                s += __shfl_xor(s, 2, 64);
                s += __shfl_xor(s, 4, 64);
                s += __shfl_xor(s, 8, 64);
                if (lr == 0) {
                    const int m = mBase + waveM + mi * 16 + lq * 4 + r;
                    atomicAdd(&aux[m], s);
                }
            }
        }
    }
}

// ---------------------------------------------------------------------------
extern "C" void kernel_launch(void* const* d_in, const int* in_sizes, int n_in,
                              void* d_out, int out_size, void* d_ws, size_t ws_size,
                              hipStream_t stream) {
    const float* x   = (const float*)d_in[0];
    const float* n1w = (const float*)d_in[1];
    const float* w1  = (const float*)d_in[2];
    const float* b1  = (const float*)d_in[3];
    const float* n2w = (const float*)d_in[4];
    const float* w2a = (const float*)d_in[5];
    const float* b2a = (const float*)d_in[6];
    const float* w2b = (const float*)d_in[7];
    const float* b2b = (const float*)d_in[8];
    float* y = (float*)d_out;

    char* w = (char*)d_ws;
    float*  inv1  = (float*)(w + 0);
    float*  csum  = (float*)(w + 131072);    // also rs2 after scan (64KB head)
    bf16_t* hilo  = (bf16_t*)(w + 1179648);
    float*  Pmat  = (float*)(w + 2228224);
    bf16_t* W1cat = (bf16_t*)(w + 5373952);
    bf16_t* W2at  = (bf16_t*)(w + 9568256);
    bf16_t* W2bt  = (bf16_t*)(w + 17956864);
    bf16_t* outb  = (bf16_t*)(w + 26345472);
    bf16_t* state = (bf16_t*)(w + 59899904);
    bf16_t* hbuf  = state;
    float*  rs2   = csum;                    // csum dead after scan_offsets_hilo

    rms_rows_f32<<<dim3(BT_ / 4), dim3(256), 0, stream>>>(x, inv1);
    scan_emit_local<<<dim3(B_ * NCH_, C_ / 256), dim3(256), 0, stream>>>(x, inv1, n1w, state, csum);
    scan_offsets_hilo<<<dim3(B_ * C_ / 256), dim3(256), 0, stream>>>(csum, hilo);
    transpose_all<<<dim3(10240), dim3(256), 0, stream>>>(
        w1, w2a, w2b, n2w, b1, W1cat, W2at, W2bt, Pmat, rs2);
    gemm128<4, float, float><<<dim3(2, C_ / 128, 4), dim3(256), 0, stream>>>(
        hilo, W1cat, nullptr, nullptr, Pmat, C_, 512, 2048, 2048);
    // GEMM1: M=16384, N=1024, K=1024 -> 64x8 = 512 blocks (512 thr, +fused rms)
    gemm_bt<0, float, bf16_t><<<dim3(BT_ / 256, C_ / 128), dim3(512), 0, stream>>>(
        state, W1cat, nullptr, x, nullptr, Pmat, rs2, outb, C_, C_, C_, 2048);
    for (int c = 0; c < BT_ / MCHUNK; c++) {
        const bf16_t* Ao = outb + (size_t)c * MCHUNK * C_;
        float* yo = y + (size_t)c * MCHUNK * C_;
        // GEMM2a: M=8192, N=4096, K=1024 -> 32x32 = 1024 blocks (512 thr)
        gemm_bt<1, float, bf16_t><<<dim3(MCHUNK / 256, H_ / 128), dim3(512), 0, stream>>>(
            Ao, W2at, b2a, nullptr, rs2 + c * MCHUNK, nullptr, nullptr, hbuf, H_, C_, C_, C_);
        // GEMM2b: M=8192, N=1024, K=4096 -> 64x8 = 512 blocks (256 thr, R11 config)
        gemm128<2, bf16_t, float><<<dim3(MCHUNK / 128, C_ / 128), dim3(256), 0, stream>>>(
            hbuf, W2bt, b2b, Ao, yo, C_, H_, H_, H_);
    }
}

// Round 14
// 554.040 us; speedup vs baseline: 1.1099x; 1.0414x over previous
//
#include <hip/hip_runtime.h>

#define B_     4
#define T_     4096
#define C_     1024
#define H_     4096
#define BT_    (B_ * T_)
#define NCH_   64
#define CHLEN_ 64
#define MCHUNK 8192   // rows per h-chunk for GEMM2a/2b (2 chunks)

typedef __bf16 bf16_t;
typedef __bf16 bf16x8 __attribute__((ext_vector_type(8)));
typedef float  f32x4  __attribute__((ext_vector_type(4)));

__device__ __forceinline__ float hs_f(float v) {
    return fminf(fmaxf((v + 3.0f) * (1.0f / 6.0f), 0.0f), 1.0f) - 0.5f;
}

__device__ __forceinline__ void gld_lds16(const bf16_t* g, bf16_t* l) {
    __builtin_amdgcn_global_load_lds((const __attribute__((address_space(1))) void*)g,
                                     (__attribute__((address_space(3))) void*)l,
                                     16, 0, 0);
}

// ---------------------------------------------------------------------------
__global__ __launch_bounds__(256) void rms_rows_f32(const float* __restrict__ X,
                                                    float* __restrict__ inv) {
    const int wave = threadIdx.x >> 6, lane = threadIdx.x & 63;
    const int row = blockIdx.x * 4 + wave;
    const float* xr = X + (size_t)row * C_;
    float s = 0.0f;
    #pragma unroll
    for (int p = 0; p < 4; p++) {
        float4 v = *(const float4*)(xr + p * 256 + lane * 4);
        s += v.x * v.x + v.y * v.y + v.z * v.z + v.w * v.w;
    }
    #pragma unroll
    for (int o = 32; o > 0; o >>= 1) s += __shfl_down(s, o, 64);
    if (lane == 0) inv[row] = rsqrtf(s * (1.0f / C_) + 1e-6f);
}

// ---------------------------------------------------------------------------
__global__ __launch_bounds__(256) void scan_emit_local(const float* __restrict__ X,
                                                       const float* __restrict__ inv1,
                                                       const float* __restrict__ nw,
                                                       bf16_t* __restrict__ state,
                                                       float* __restrict__ csum) {
    const int bch = blockIdx.x;
    const int b = bch >> 6, ch = bch & 63;
    const int c = blockIdx.y * 256 + threadIdx.x;
    const float wgt = nw[c];
    const int rbase = b * T_ + ch * CHLEN_;
    const size_t xbase = (size_t)rbase * C_ + c;
    float acc = 0.0f;
    for (int i = 0; i < CHLEN_; i++) {
        acc += hs_f(X[xbase + (size_t)i * C_] * inv1[rbase + i] * wgt);
        state[(size_t)(rbase + i) * C_ + c] = (bf16_t)acc;
    }
    csum[(size_t)bch * C_ + c] = acc;
}

__global__ __launch_bounds__(256) void scan_offsets_hilo(const float* __restrict__ csum,
                                                         bf16_t* __restrict__ hilo) {
    const int idx = blockIdx.x * 256 + threadIdx.x;   // b*1024 + c
    const int b = idx >> 10, c = idx & 1023;
    const size_t base = (size_t)b * NCH_ * C_ + c;
    float v[NCH_];
    #pragma unroll
    for (int ch = 0; ch < NCH_; ch++)
        v[ch] = csum[base + (size_t)ch * C_];
    float run = 0.0f;
    #pragma unroll
    for (int ch = 0; ch < NCH_; ch++) {
        const size_t row = (size_t)(b * NCH_ + ch) * 2048 + c;
        const bf16_t hi = (bf16_t)run;
        hilo[row] = hi;
        hilo[row + 1024] = (bf16_t)(run - (float)hi);
        run += v[ch];
    }
}

// ---------------------------------------------------------------------------
// All 3 weight transposes + Pmat seed + rs2 zero in ONE launch (R12 merge).
// ---------------------------------------------------------------------------
__global__ __launch_bounds__(256) void transpose_all(const float* __restrict__ w1,
                                                     const float* __restrict__ w2a,
                                                     const float* __restrict__ w2b,
                                                     const float* __restrict__ n2w,
                                                     const float* __restrict__ b1,
                                                     bf16_t* __restrict__ W1cat,
                                                     bf16_t* __restrict__ W2at,
                                                     bf16_t* __restrict__ W2bt,
                                                     float* __restrict__ Pmat,
                                                     float* __restrict__ rs2) {
    const int flat = blockIdx.x;
    if (flat >= 9216) {                      // init tail
        const int i = (flat - 9216) * 256 + threadIdx.x;
        Pmat[i] = b1[i & (C_ - 1)];
        if (i < BT_) rs2[i] = 0.0f;
        return;
    }
    __shared__ float tile[32][33];
    const float* src; bf16_t* dst; const float* scale;
    int N, ldd, dupOff, bx, by;
    if (flat < 1024) {          // w1 -> W1cat: K=C,N=C, ldd=2048, dup
        src = w1; dst = W1cat; scale = nullptr;
        N = C_; ldd = 2048; dupOff = 1024;
        bx = flat & 31; by = flat >> 5;               // 32 x 32
    } else if (flat < 5120) {   // w2a -> W2at: K=C,N=H, ldd=C, scale=n2w
        const int f = flat - 1024;
        src = w2a; dst = W2at; scale = n2w;
        N = H_; ldd = C_; dupOff = 0;
        bx = f & 127; by = f >> 7;                    // 128 x 32
    } else {                    // w2b -> W2bt: K=H,N=C, ldd=H
        const int f = flat - 5120;
        src = w2b; dst = W2bt; scale = nullptr;
        N = C_; ldd = H_; dupOff = 0;
        bx = f & 31; by = f >> 5;                     // 32 x 128
    }
    const int n0 = bx * 32, k0 = by * 32;
    const int tx = threadIdx.x & 31, ty = threadIdx.x >> 5;
    #pragma unroll
    for (int j = 0; j < 4; j++) {
        const int kk = ty + j * 8;
        float v = src[(size_t)(k0 + kk) * N + n0 + tx];
        if (scale) v *= scale[k0 + kk];
        tile[kk][tx] = v;
    }
    __syncthreads();
    #pragma unroll
    for (int j = 0; j < 4; j++) {
        const int nn = ty + j * 8;
        const bf16_t v = (bf16_t)tile[tx][nn];
        dst[(size_t)(n0 + nn) * ldd + k0 + tx] = v;
        if (dupOff) dst[(size_t)(n0 + nn) * ldd + dupOff + k0 + tx] = v;
    }
}

// ---------------------------------------------------------------------------
// 128x128 2-deep pipelined GEMM, 256 thr (R8/R11-verified: VGPR~108-124,
// 16 waves/CU, no spill, no launch-bounds cap).
// R14: GEMM1 (MODE 0) moved BACK here from the 512-thr kernel — R13 PMC
// showed MODE 0's epilogue pushes natural VGPR above the (512,4) cap of 128,
// collapsing the allocator to 64 (acc spill; cold instance 175 us with
// scratch-alloc stall). Per-MODE rule: cap must be >= that MODE's natural.
//
//   prologue: STAGE(buf0,k0); STAGE(buf1,k0+32)
//   iter t:   vmcnt(4|0) -> s_barrier -> ds_read+MFMA(buf t&1) -> s_barrier
//             -> STAGE(buf t&1, k+64)
// Swizzle (T2, R6-verified): phys slot s' = s ^ ((row>>1)&3); both-sides
// (rule #21). Ascending-K 32-groups -> bitwise-same numerics.
//
// MODE 0: out bf16 = hs(acc + pmat[(m>>6)*N+n]) * xf32[m*N+n]; + fused row
//         sum-of-squares of bf16-rounded out into aux[m] (atomicAdd).
// MODE 2: out f32  = acc + bias[n] + (f32)extra_bf16[m*N+n]   (GEMM2b)
// MODE 4: atomicAdd(out f32, acc)                             (split-K P-GEMM)
// ---------------------------------------------------------------------------
template <int MODE, typename ET, typename OT>
__global__ __launch_bounds__(256) void gemm128(const bf16_t* __restrict__ A,
                                               const bf16_t* __restrict__ Bt,
                                               const float* __restrict__ bias,
                                               const ET* __restrict__ extra,
                                               const float* __restrict__ pmat,
                                               float* __restrict__ aux,
                                               OT* __restrict__ Cmat,
                                               int N, int K, int lda, int ldb) {
    __shared__ __align__(16) bf16_t As[2][128 * 32];
    __shared__ __align__(16) bf16_t Bs[2][128 * 32];
    const int tid = threadIdx.x;

    const int nwgx = gridDim.x;
    const int flat0 = blockIdx.y * nwgx + blockIdx.x;
    int mTile, nTile;
    if ((nwgx & 7) == 0) {                  // XCD m-slice mapping (R3 win)
        const int xcd = flat0 & 7;
        const int loc = flat0 >> 3;
        const int mpx = nwgx >> 3;
        mTile = xcd * mpx + (loc % mpx);
        nTile = loc / mpx;
    } else {
        mTile = blockIdx.x;
        nTile = blockIdx.y;
    }
    const int mBase = mTile * 128;
    const int nBase = nTile * 128;
    const size_t kOff = (size_t)blockIdx.z * K;

    const int wave = tid >> 6;
    const int lane = tid & 63;
    const int waveM = (wave & 1) * 64;
    const int waveN = (wave >> 1) * 64;
    const int lr = lane & 15;
    const int lq = lane >> 4;

    f32x4 acc[4][4] = {};

    const int e0 = tid * 8;
    const int r0 = e0 >> 5, c0 = (((e0 >> 3) & 3) ^ ((r0 >> 1) & 3)) << 3;
    const int e1 = 2048 + tid * 8;
    const int r1 = e1 >> 5, c1 = (((e1 >> 3) & 3) ^ ((r1 >> 1) & 3)) << 3;

    const bf16_t* Ag0 = A + (size_t)(mBase + r0) * lda + kOff + c0;
    const bf16_t* Ag1 = A + (size_t)(mBase + r1) * lda + kOff + c1;
    const bf16_t* Bg0 = Bt + (size_t)(nBase + r0) * ldb + kOff + c0;
    const bf16_t* Bg1 = Bt + (size_t)(nBase + r1) * ldb + kOff + c1;

    auto stage = [&](int buf, int kb) {
        gld_lds16(Ag0 + kb, As[buf] + e0);
        gld_lds16(Ag1 + kb, As[buf] + e1);
        gld_lds16(Bg0 + kb, Bs[buf] + e0);
        gld_lds16(Bg1 + kb, Bs[buf] + e1);
    };

    stage(0, 0);
    if (32 < K) stage(1, 32);

    int cur = 0;
    for (int kb = 0; kb < K; kb += 32) {
        if (kb + 32 < K) asm volatile("s_waitcnt vmcnt(4)" ::: "memory");
        else             asm volatile("s_waitcnt vmcnt(0)" ::: "memory");
        __builtin_amdgcn_s_barrier();

        bf16x8 af[4], bfr[4];
        #pragma unroll
        for (int mi = 0; mi < 4; mi++) {
            const int R = waveM + mi * 16 + lr;
            af[mi] = *(const bf16x8*)(As[cur] + R * 32 + ((lq ^ ((R >> 1) & 3)) << 3));
        }
        #pragma unroll
        for (int ni = 0; ni < 4; ni++) {
            const int R = waveN + ni * 16 + lr;
            bfr[ni] = *(const bf16x8*)(Bs[cur] + R * 32 + ((lq ^ ((R >> 1) & 3)) << 3));
        }
        #pragma unroll
        for (int mi = 0; mi < 4; mi++)
            #pragma unroll
            for (int ni = 0; ni < 4; ni++)
                acc[mi][ni] = __builtin_amdgcn_mfma_f32_16x16x32_bf16(
                    af[mi], bfr[ni], acc[mi][ni], 0, 0, 0);

        __builtin_amdgcn_s_barrier();
        if (kb + 64 < K) stage(cur, kb + 64);
        cur ^= 1;
    }

    // Epilogue. C/D layout: col(n)=lane&15, row(m)=(lane>>4)*4+reg.
    float sq[4][4];                          // MODE 0: per-(mi,r) sum v^2
    if (MODE == 0) {
        #pragma unroll
        for (int a = 0; a < 4; a++)
            #pragma unroll
            for (int b = 0; b < 4; b++) sq[a][b] = 0.0f;
    }
    #pragma unroll
    for (int ni = 0; ni < 4; ni++) {
        const int n = nBase + waveN + ni * 16 + lr;
        const float bz = (MODE == 2) ? bias[n] : 0.0f;
        #pragma unroll
        for (int mi = 0; mi < 4; mi++) {
            #pragma unroll
            for (int r = 0; r < 4; r++) {
                const int m = mBase + waveM + mi * 16 + lq * 4 + r;
                float v = acc[mi][ni][r];
                if (MODE == 0) {
                    v = hs_f(v + pmat[(size_t)(m >> 6) * N + n]) * (float)extra[(size_t)m * N + n];
                    const OT vs = (OT)v;
                    Cmat[(size_t)m * N + n] = vs;
                    const float vb = (float)vs;      // bf16-rounded, matches old pass
                    sq[mi][r] += vb * vb;
                } else if (MODE == 2) {
                    v = v + bz + (float)extra[(size_t)m * N + n];
                    Cmat[(size_t)m * N + n] = (OT)v;
                } else {
                    atomicAdd((float*)&Cmat[(size_t)m * N + n], v);
                }
            }
        }
    }
    if (MODE == 0) {
        // Reduce over the 16-lane column group (lr); lanes lr==0 own the row.
        #pragma unroll
        for (int mi = 0; mi < 4; mi++) {
            #pragma unroll
            for (int r = 0; r < 4; r++) {
                float s = sq[mi][r];
                s += __shfl_xor(s, 1, 64);
                s += __shfl_xor(s, 2, 64);
                s += __shfl_xor(s, 4, 64);
                s += __shfl_xor(s, 8, 64);
                if (lr == 0) {
                    const int m = mBase + waveM + mi * 16 + lq * 4 + r;
                    atomicAdd(&aux[m], s);
                }
            }
        }
    }
}

// ---------------------------------------------------------------------------
// 256x128 2-deep pipelined GEMM, 512 thr = 8 waves (4M x 2N), per-wave 64x64.
// __launch_bounds__(512, 4): VGPR cap 128 >= MODE 1's natural ~108 -> no
// spill (R13-verified: GEMM2a dropped out of top-5, from 105 us).
// ONLY MODE 1 lives here — MODE 0's bigger epilogue exceeds the cap (R13).
//
// MODE 1: out bf16 = relu(rsqrt(rs2[m]/C+eps)*acc + bias[n])  (GEMM2a)
// ---------------------------------------------------------------------------
template <int MODE, typename ET, typename OT>
__global__ __launch_bounds__(512, 4) void gemm_bt(const bf16_t* __restrict__ A,
                                                  const bf16_t* __restrict__ Bt,
                                                  const float* __restrict__ bias,
                                                  const ET* __restrict__ extra,
                                                  const float* __restrict__ rowscale,
                                                  OT* __restrict__ Cmat,
                                                  int N, int K, int lda, int ldb) {
    __shared__ __align__(16) bf16_t As[2][256 * 32];   // 2 x 16 KB
    __shared__ __align__(16) bf16_t Bs[2][128 * 32];   // 2 x  8 KB
    const int tid = threadIdx.x;

    const int nwgx = gridDim.x;
    const int flat0 = blockIdx.y * nwgx + blockIdx.x;
    int mTile, nTile;
    if ((nwgx & 7) == 0) {                  // XCD m-slice mapping (R3 win)
        const int xcd = flat0 & 7;
        const int loc = flat0 >> 3;
        const int mpx = nwgx >> 3;
        mTile = xcd * mpx + (loc % mpx);
        nTile = loc / mpx;
    } else {
        mTile = blockIdx.x;
        nTile = blockIdx.y;
    }
    const int mBase = mTile * 256;
    const int nBase = nTile * 128;

    const int wave = tid >> 6;
    const int lane = tid & 63;
    const int waveM = (wave >> 1) * 64;     // 4 M-quarters
    const int waveN = (wave & 1) * 64;      // 2 N-halves
    const int lr = lane & 15;
    const int lq = lane >> 4;

    f32x4 acc[4][4] = {};

    const int a0 = tid * 8;
    const int ar0 = a0 >> 5, ac0 = (((a0 >> 3) & 3) ^ ((ar0 >> 1) & 3)) << 3;
    const int a1 = 4096 + tid * 8;
    const int ar1 = a1 >> 5, ac1 = (((a1 >> 3) & 3) ^ ((ar1 >> 1) & 3)) << 3;
    const int b0 = tid * 8;
    const int br0 = b0 >> 5, bc0 = (((b0 >> 3) & 3) ^ ((br0 >> 1) & 3)) << 3;

    const bf16_t* Ag0 = A + (size_t)(mBase + ar0) * lda + ac0;
    const bf16_t* Ag1 = A + (size_t)(mBase + ar1) * lda + ac1;
    const bf16_t* Bg0 = Bt + (size_t)(nBase + br0) * ldb + bc0;

    auto stage = [&](int buf, int kb) {
        gld_lds16(Ag0 + kb, As[buf] + a0);
        gld_lds16(Ag1 + kb, As[buf] + a1);
        gld_lds16(Bg0 + kb, Bs[buf] + b0);
    };

    stage(0, 0);
    if (32 < K) stage(1, 32);

    int cur = 0;
    for (int kb = 0; kb < K; kb += 32) {
        if (kb + 32 < K) asm volatile("s_waitcnt vmcnt(3)" ::: "memory");
        else             asm volatile("s_waitcnt vmcnt(0)" ::: "memory");
        __builtin_amdgcn_s_barrier();       // buf cur staged for all waves

        bf16x8 af[4], bfr[4];
        #pragma unroll
        for (int mi = 0; mi < 4; mi++) {
            const int R = waveM + mi * 16 + lr;
            af[mi] = *(const bf16x8*)(As[cur] + R * 32 + ((lq ^ ((R >> 1) & 3)) << 3));
        }
        #pragma unroll
        for (int ni = 0; ni < 4; ni++) {
            const int R = waveN + ni * 16 + lr;
            bfr[ni] = *(const bf16x8*)(Bs[cur] + R * 32 + ((lq ^ ((R >> 1) & 3)) << 3));
        }
        #pragma unroll
        for (int mi = 0; mi < 4; mi++)
            #pragma unroll
            for (int ni = 0; ni < 4; ni++)
                acc[mi][ni] = __builtin_amdgcn_mfma_f32_16x16x32_bf16(
                    af[mi], bfr[ni], acc[mi][ni], 0, 0, 0);

        __builtin_amdgcn_s_barrier();       // all waves done reading buf cur
        if (kb + 64 < K) stage(cur, kb + 64);
        cur ^= 1;
    }

    // Epilogue (MODE 1). C/D layout: col(n)=lane&15, row(m)=(lane>>4)*4+reg.
    float invm[4][4];
    #pragma unroll
    for (int mi = 0; mi < 4; mi++)
        #pragma unroll
        for (int r = 0; r < 4; r++) {
            const int m = mBase + waveM + mi * 16 + lq * 4 + r;
            invm[mi][r] = rsqrtf(rowscale[m] * (1.0f / C_) + 1e-6f);
        }
    #pragma unroll
    for (int ni = 0; ni < 4; ni++) {
        const int n = nBase + waveN + ni * 16 + lr;
        const float bz = bias[n];
        #pragma unroll
        for (int mi = 0; mi < 4; mi++) {
            #pragma unroll
            for (int r = 0; r < 4; r++) {
                const int m = mBase + waveM + mi * 16 + lq * 4 + r;
                const float v = fmaxf(invm[mi][r] * acc[mi][ni][r] + bz, 0.0f);
                Cmat[(size_t)m * N + n] = (OT)v;
            }
        }
    }
}

// ---------------------------------------------------------------------------
extern "C" void kernel_launch(void* const* d_in, const int* in_sizes, int n_in,
                              void* d_out, int out_size, void* d_ws, size_t ws_size,
                              hipStream_t stream) {
    const float* x   = (const float*)d_in[0];
    const float* n1w = (const float*)d_in[1];
    const float* w1  = (const float*)d_in[2];
    const float* b1  = (const float*)d_in[3];
    const float* n2w = (const float*)d_in[4];
    const float* w2a = (const float*)d_in[5];
    const float* b2a = (const float*)d_in[6];
    const float* w2b = (const float*)d_in[7];
    const float* b2b = (const float*)d_in[8];
    float* y = (float*)d_out;

    char* w = (char*)d_ws;
    float*  inv1  = (float*)(w + 0);
    float*  csum  = (float*)(w + 131072);    // also rs2 after scan (64KB head)
    bf16_t* hilo  = (bf16_t*)(w + 1179648);
    float*  Pmat  = (float*)(w + 2228224);
    bf16_t* W1cat = (bf16_t*)(w + 5373952);
    bf16_t* W2at  = (bf16_t*)(w + 9568256);
    bf16_t* W2bt  = (bf16_t*)(w + 17956864);
    bf16_t* outb  = (bf16_t*)(w + 26345472);
    bf16_t* state = (bf16_t*)(w + 59899904);
    bf16_t* hbuf  = state;
    float*  rs2   = csum;                    // csum dead after scan_offsets_hilo

    rms_rows_f32<<<dim3(BT_ / 4), dim3(256), 0, stream>>>(x, inv1);
    scan_emit_local<<<dim3(B_ * NCH_, C_ / 256), dim3(256), 0, stream>>>(x, inv1, n1w, state, csum);
    scan_offsets_hilo<<<dim3(B_ * C_ / 256), dim3(256), 0, stream>>>(csum, hilo);
    transpose_all<<<dim3(10240), dim3(256), 0, stream>>>(
        w1, w2a, w2b, n2w, b1, W1cat, W2at, W2bt, Pmat, rs2);
    // P-GEMM: split-K x4, atomicAdd into Pmat (seeded with b1)
    gemm128<4, float, float><<<dim3(2, C_ / 128, 4), dim3(256), 0, stream>>>(
        hilo, W1cat, nullptr, nullptr, nullptr, nullptr, Pmat, C_, 512, 2048, 2048);
    // GEMM1: M=16384, N=1024, K=1024 -> 128x8 = 1024 blocks (256 thr, R11 config,
    // fused rms sumsq into rs2)
    gemm128<0, float, bf16_t><<<dim3(BT_ / 128, C_ / 128), dim3(256), 0, stream>>>(
        state, W1cat, nullptr, x, Pmat, rs2, outb, C_, C_, C_, 2048);
    for (int c = 0; c < BT_ / MCHUNK; c++) {
        const bf16_t* Ao = outb + (size_t)c * MCHUNK * C_;
        float* yo = y + (size_t)c * MCHUNK * C_;
        // GEMM2a: M=8192, N=4096, K=1024 -> 32x32 = 1024 blocks (512 thr, (512,4))
        gemm_bt<1, float, bf16_t><<<dim3(MCHUNK / 256, H_ / 128), dim3(512), 0, stream>>>(
            Ao, W2at, b2a, nullptr, rs2 + c * MCHUNK, hbuf, H_, C_, C_, C_);
        // GEMM2b: M=8192, N=1024, K=4096 -> 64x8 = 512 blocks (256 thr)
        gemm128<2, bf16_t, float><<<dim3(MCHUNK / 128, C_ / 128), dim3(256), 0, stream>>>(
            hbuf, W2bt, b2b, Ao, nullptr, nullptr, yo, C_, H_, H_, H_);
    }
}